// Round 1
// baseline (2450.289 us; speedup 1.0000x reference)
//
#include <hip/hip_runtime.h>

#define N_NODES 50000
#define N_EDGES 800000
#define C_IN 128
#define C_OUT 256
#define BN_EPS 1e-5f

// Order-preserving float -> uint map (monotone): uint compare == float compare.
__device__ __forceinline__ unsigned int f2key(float f) {
    unsigned int b = __float_as_uint(f);
    return (b & 0x80000000u) ? ~b : (b | 0x80000000u);
}
__device__ __forceinline__ float key2f(unsigned int k) {
    unsigned int b = (k & 0x80000000u) ? (k & 0x7FFFFFFFu) : ~k;
    return __uint_as_float(b);
}
// f2key(-inf): sentinel for "empty segment"
#define SENT 0x007FFFFFu

// ---------------------------------------------------------------------------
// Kernel A: u = x @ theta^T  (channels 0..255 of combined output)
//           v = x @ (phi - theta)^T (channels 256..511)
// Tile: 64 nodes x 64 channels, K=128 fully resident in LDS.
// Row pad +1 float => 2-way max bank aliasing (free on gfx950).
// ---------------------------------------------------------------------------
__global__ __launch_bounds__(256) void gemm_uv(
    const float* __restrict__ x,      // [N, 128]
    const float* __restrict__ theta,  // [256, 128]
    const float* __restrict__ phi,    // [256, 128]
    float* __restrict__ u,            // [N, 256]
    float* __restrict__ v)            // [N, 256]
{
    __shared__ float xs[64][C_IN + 1];
    __shared__ float wsm[64][C_IN + 1];

    const int n0 = blockIdx.x * 64;
    const int c0 = blockIdx.y * 64;  // 0..511, never straddles 256
    const int tid = threadIdx.x;

    // Stage x tile: 64 rows x 128 cols = 2048 float4 across 256 threads.
    #pragma unroll
    for (int i = 0; i < 8; ++i) {
        int f = tid + i * 256;   // 0..2047
        int r = f >> 5;          // 32 float4 per row
        int k4 = f & 31;
        float4 val = make_float4(0.f, 0.f, 0.f, 0.f);
        int n = n0 + r;
        if (n < N_NODES) val = *(const float4*)(x + (size_t)n * C_IN + k4 * 4);
        xs[r][k4 * 4 + 0] = val.x;
        xs[r][k4 * 4 + 1] = val.y;
        xs[r][k4 * 4 + 2] = val.z;
        xs[r][k4 * 4 + 3] = val.w;
    }
    // Stage weight tile (theta, or phi - theta).
    const bool is_phi = (c0 >= C_OUT);
    const int cb = is_phi ? (c0 - C_OUT) : c0;
    #pragma unroll
    for (int i = 0; i < 8; ++i) {
        int f = tid + i * 256;
        int r = f >> 5;
        int k4 = f & 31;
        float4 tv = *(const float4*)(theta + (size_t)(cb + r) * C_IN + k4 * 4);
        float4 val = tv;
        if (is_phi) {
            float4 pv = *(const float4*)(phi + (size_t)(cb + r) * C_IN + k4 * 4);
            val = make_float4(pv.x - tv.x, pv.y - tv.y, pv.z - tv.z, pv.w - tv.w);
        }
        wsm[r][k4 * 4 + 0] = val.x;
        wsm[r][k4 * 4 + 1] = val.y;
        wsm[r][k4 * 4 + 2] = val.z;
        wsm[r][k4 * 4 + 3] = val.w;
    }
    __syncthreads();

    const int tr = tid & 15;   // node micro-tile index
    const int tc = tid >> 4;   // channel micro-tile index
    float acc[4][4];
    #pragma unroll
    for (int i = 0; i < 4; ++i)
        #pragma unroll
        for (int j = 0; j < 4; ++j) acc[i][j] = 0.f;

    for (int k = 0; k < C_IN; ++k) {
        float a[4], b[4];
        #pragma unroll
        for (int i = 0; i < 4; ++i) a[i] = xs[tr * 4 + i][k];
        #pragma unroll
        for (int j = 0; j < 4; ++j) b[j] = wsm[tc * 4 + j][k];
        #pragma unroll
        for (int i = 0; i < 4; ++i)
            #pragma unroll
            for (int j = 0; j < 4; ++j)
                acc[i][j] = fmaf(a[i], b[j], acc[i][j]);
    }

    #pragma unroll
    for (int i = 0; i < 4; ++i) {
        int n = n0 + tr * 4 + i;
        if (n >= N_NODES) continue;
        #pragma unroll
        for (int j = 0; j < 4; ++j) {
            int c = c0 + tc * 4 + j;
            if (c < C_OUT) u[(size_t)n * C_OUT + c] = acc[i][j];
            else           v[(size_t)n * C_OUT + (c - C_OUT)] = acc[i][j];
        }
    }
}

// ---------------------------------------------------------------------------
// Kernel B: init max-buffer (lives in d_out) to transformed(-inf).
// ---------------------------------------------------------------------------
__global__ __launch_bounds__(256) void init_m(uint4* __restrict__ m) {
    int i = blockIdx.x * 256 + threadIdx.x;
    if (i < N_NODES * C_OUT / 4) m[i] = make_uint4(SENT, SENT, SENT, SENT);
}

// ---------------------------------------------------------------------------
// Kernel C: edge scatter-max. One thread = one edge x 4 channels.
// Consecutive threads -> consecutive float4 of the same u row (coalesced).
// ---------------------------------------------------------------------------
__global__ __launch_bounds__(256) void edge_max(
    const int* __restrict__ src, const int* __restrict__ dst,
    const float* __restrict__ u, unsigned int* __restrict__ m)
{
    const int t = blockIdx.x * 256 + threadIdx.x;
    const int e = t >> 6;          // 64 channel-groups per edge
    if (e >= N_EDGES) return;
    const int cg = (t & 63) * 4;
    const int s = src[e];
    const int d = dst[e];
    const float4 uv = *(const float4*)(u + (size_t)d * C_OUT + cg);
    unsigned int* mp = m + (size_t)s * C_OUT + cg;
    atomicMax(mp + 0, f2key(uv.x));
    atomicMax(mp + 1, f2key(uv.y));
    atomicMax(mp + 2, f2key(uv.z));
    atomicMax(mp + 3, f2key(uv.w));
}

// ---------------------------------------------------------------------------
// Kernel D: agg = empty ? 0 : relu(v + max_u), in place in d_out.
// Also per-channel sum / sumsq partials (block handles 64 rows x 256 ch).
// ---------------------------------------------------------------------------
__global__ __launch_bounds__(256) void agg_stats(
    const float* __restrict__ v, float* __restrict__ out,
    float* __restrict__ sums, float* __restrict__ sumsq)
{
    const int c = threadIdx.x;
    const int r0 = blockIdx.x * 64;
    unsigned int* mb = (unsigned int*)out;
    float s1 = 0.f, s2 = 0.f;
    for (int i = 0; i < 64; ++i) {
        int n = r0 + i;
        if (n >= N_NODES) break;
        unsigned int key = mb[(size_t)n * C_OUT + c];
        float a = 0.f;
        if (key != SENT) {
            a = v[(size_t)n * C_OUT + c] + key2f(key);
            a = fmaxf(a, 0.f);
        }
        out[(size_t)n * C_OUT + c] = a;
        s1 += a;
        s2 += a * a;
    }
    atomicAdd(&sums[c], s1);
    atomicAdd(&sumsq[c], s2);
}

// ---------------------------------------------------------------------------
// Kernel E: BatchNorm (batch stats, biased var) + ReLU, in place.
// ---------------------------------------------------------------------------
__global__ __launch_bounds__(256) void bn_apply(
    float* __restrict__ out, const float* __restrict__ sums,
    const float* __restrict__ sumsq, const float* __restrict__ gamma,
    const float* __restrict__ beta)
{
    const int idx = blockIdx.x * 256 + threadIdx.x;
    if (idx >= N_NODES * C_OUT) return;
    const int c = idx & (C_OUT - 1);
    const float inv_n = 1.f / (float)N_NODES;
    const float mean = sums[c] * inv_n;
    const float var = sumsq[c] * inv_n - mean * mean;
    const float scale = rsqrtf(var + BN_EPS) * gamma[c];
    float val = (out[idx] - mean) * scale + beta[c];
    out[idx] = fmaxf(val, 0.f);
}

extern "C" void kernel_launch(void* const* d_in, const int* in_sizes, int n_in,
                              void* d_out, int out_size, void* d_ws, size_t ws_size,
                              hipStream_t stream) {
    const float* x     = (const float*)d_in[0];
    const int*   src   = (const int*)d_in[1];
    const int*   dst   = (const int*)d_in[2];
    const float* theta = (const float*)d_in[3];
    const float* phi   = (const float*)d_in[4];
    const float* gamma = (const float*)d_in[5];
    const float* beta  = (const float*)d_in[6];
    float* out = (float*)d_out;

    char* ws = (char*)d_ws;
    const size_t uv_bytes = (size_t)N_NODES * C_OUT * sizeof(float);
    float* u     = (float*)ws;
    float* v     = (float*)(ws + uv_bytes);
    float* sums  = (float*)(ws + 2 * uv_bytes);
    float* sumsq = sums + C_OUT;

    hipMemsetAsync(sums, 0, 2 * C_OUT * sizeof(float), stream);

    dim3 gA((N_NODES + 63) / 64, (2 * C_OUT) / 64);
    gemm_uv<<<gA, 256, 0, stream>>>(x, theta, phi, u, v);

    init_m<<<(N_NODES * C_OUT / 4 + 255) / 256, 256, 0, stream>>>((uint4*)out);

    edge_max<<<(N_EDGES * 64) / 256, 256, 0, stream>>>(src, dst, u, (unsigned int*)out);

    agg_stats<<<(N_NODES + 63) / 64, 256, 0, stream>>>(v, out, sums, sumsq);

    bn_apply<<<(N_NODES * C_OUT + 255) / 256, 256, 0, stream>>>(out, sums, sumsq, gamma, beta);
}

// Round 2
// 839.442 us; speedup vs baseline: 2.9189x; 2.9189x over previous
//
#include <hip/hip_runtime.h>

#define N_NODES 50000
#define N_EDGES 800000
#define C_IN 128
#define C_OUT 256
#define BN_EPS 1e-5f

// ---------------------------------------------------------------------------
// Kernel A: u = x @ theta^T  (channels 0..255 of combined output)
//           v = x @ (phi - theta)^T (channels 256..511)
// Identity: theta@(xj-xi) + phi@xi = u[dst] + v[src]; relu/max commute so the
// edge pass only needs scatter-max over u rows.
// ---------------------------------------------------------------------------
__global__ __launch_bounds__(256) void gemm_uv(
    const float* __restrict__ x,      // [N, 128]
    const float* __restrict__ theta,  // [256, 128]
    const float* __restrict__ phi,    // [256, 128]
    float* __restrict__ u,            // [N, 256]
    float* __restrict__ v)            // [N, 256]
{
    __shared__ float xs[64][C_IN + 1];
    __shared__ float wsm[64][C_IN + 1];

    const int n0 = blockIdx.x * 64;
    const int c0 = blockIdx.y * 64;  // 0..511, never straddles 256
    const int tid = threadIdx.x;

    #pragma unroll
    for (int i = 0; i < 8; ++i) {
        int f = tid + i * 256;   // 0..2047
        int r = f >> 5;          // 32 float4 per row
        int k4 = f & 31;
        float4 val = make_float4(0.f, 0.f, 0.f, 0.f);
        int n = n0 + r;
        if (n < N_NODES) val = *(const float4*)(x + (size_t)n * C_IN + k4 * 4);
        xs[r][k4 * 4 + 0] = val.x;
        xs[r][k4 * 4 + 1] = val.y;
        xs[r][k4 * 4 + 2] = val.z;
        xs[r][k4 * 4 + 3] = val.w;
    }
    const bool is_phi = (c0 >= C_OUT);
    const int cb = is_phi ? (c0 - C_OUT) : c0;
    #pragma unroll
    for (int i = 0; i < 8; ++i) {
        int f = tid + i * 256;
        int r = f >> 5;
        int k4 = f & 31;
        float4 tv = *(const float4*)(theta + (size_t)(cb + r) * C_IN + k4 * 4);
        float4 val = tv;
        if (is_phi) {
            float4 pv = *(const float4*)(phi + (size_t)(cb + r) * C_IN + k4 * 4);
            val = make_float4(pv.x - tv.x, pv.y - tv.y, pv.z - tv.z, pv.w - tv.w);
        }
        wsm[r][k4 * 4 + 0] = val.x;
        wsm[r][k4 * 4 + 1] = val.y;
        wsm[r][k4 * 4 + 2] = val.z;
        wsm[r][k4 * 4 + 3] = val.w;
    }
    __syncthreads();

    const int tr = tid & 15;
    const int tc = tid >> 4;
    float acc[4][4];
    #pragma unroll
    for (int i = 0; i < 4; ++i)
        #pragma unroll
        for (int j = 0; j < 4; ++j) acc[i][j] = 0.f;

    for (int k = 0; k < C_IN; ++k) {
        float a[4], b[4];
        #pragma unroll
        for (int i = 0; i < 4; ++i) a[i] = xs[tr * 4 + i][k];
        #pragma unroll
        for (int j = 0; j < 4; ++j) b[j] = wsm[tc * 4 + j][k];
        #pragma unroll
        for (int i = 0; i < 4; ++i)
            #pragma unroll
            for (int j = 0; j < 4; ++j)
                acc[i][j] = fmaf(a[i], b[j], acc[i][j]);
    }

    #pragma unroll
    for (int i = 0; i < 4; ++i) {
        int n = n0 + tr * 4 + i;
        if (n >= N_NODES) continue;
        #pragma unroll
        for (int j = 0; j < 4; ++j) {
            int c = c0 + tc * 4 + j;
            if (c < C_OUT) u[(size_t)n * C_OUT + c] = acc[i][j];
            else           v[(size_t)n * C_OUT + (c - C_OUT)] = acc[i][j];
        }
    }
}

// ---------------------------------------------------------------------------
// CSR build: histogram of src -> exclusive scan -> bucket scatter of dst.
// Only ~1.6M atomics on 50K counters vs 205M value atomics before.
// ---------------------------------------------------------------------------
__global__ __launch_bounds__(256) void hist_src(
    const int* __restrict__ src, int* __restrict__ deg)
{
    int i = blockIdx.x * 256 + threadIdx.x;
    if (i < N_EDGES) atomicAdd(&deg[src[i]], 1);
}

__global__ __launch_bounds__(1024) void scan_deg(
    const int* __restrict__ deg, int* __restrict__ off)
{
    __shared__ int buf[1024];
    const int tid = threadIdx.x;
    int carry = 0;
    for (int base = 0; base < N_NODES; base += 1024) {
        int i = base + tid;
        int val = (i < N_NODES) ? deg[i] : 0;
        buf[tid] = val;
        __syncthreads();
        for (int d = 1; d < 1024; d <<= 1) {
            int t = (tid >= d) ? buf[tid - d] : 0;
            __syncthreads();
            buf[tid] += t;
            __syncthreads();
        }
        int inc = buf[tid];
        int total = buf[1023];
        if (i < N_NODES) off[i] = carry + inc - val;  // exclusive
        carry += total;
        __syncthreads();
    }
    if (tid == 0) off[N_NODES] = carry;
}

__global__ __launch_bounds__(256) void scatter_edges(
    const int* __restrict__ src, const int* __restrict__ dst,
    int* __restrict__ cursor, int* __restrict__ edst)
{
    int i = blockIdx.x * 256 + threadIdx.x;
    if (i < N_EDGES) {
        int pos = atomicAdd(&cursor[src[i]], 1);
        edst[pos] = dst[i];
    }
}

// ---------------------------------------------------------------------------
// Gather-max + v-add + relu + per-channel stats. One 64-lane group per node
// (thread = 4 channels, float4). 4 nodes in flight per 256-thread block;
// NB nodes per block total. Edge loop unrolled x4 for load-level parallelism.
// ---------------------------------------------------------------------------
#define NB 16

__device__ __forceinline__ float4 max4(float4 a, float4 b) {
    return make_float4(fmaxf(a.x, b.x), fmaxf(a.y, b.y),
                       fmaxf(a.z, b.z), fmaxf(a.w, b.w));
}

__global__ __launch_bounds__(256) void gather_max(
    const int* __restrict__ off, const int* __restrict__ edst,
    const float* __restrict__ u, const float* __restrict__ v,
    float* __restrict__ out, float* __restrict__ sums, float* __restrict__ sumsq)
{
    const int slot = threadIdx.x >> 6;   // wave id: 4 concurrent nodes
    const int lane = threadIdx.x & 63;   // channel group
    const int c = lane * 4;

    float s1x = 0.f, s1y = 0.f, s1z = 0.f, s1w = 0.f;
    float s2x = 0.f, s2y = 0.f, s2z = 0.f, s2w = 0.f;

    const int n_base = blockIdx.x * NB;
    for (int it = 0; it < NB / 4; ++it) {
        int n = n_base + it * 4 + slot;
        if (n < N_NODES) {
            const int start = off[n];
            const int end = off[n + 1];
            float4 m = make_float4(-INFINITY, -INFINITY, -INFINITY, -INFINITY);
            int e = start;
            for (; e + 4 <= end; e += 4) {
                int d0 = edst[e + 0], d1 = edst[e + 1];
                int d2 = edst[e + 2], d3 = edst[e + 3];
                float4 a0 = *(const float4*)(u + (size_t)d0 * C_OUT + c);
                float4 a1 = *(const float4*)(u + (size_t)d1 * C_OUT + c);
                float4 a2 = *(const float4*)(u + (size_t)d2 * C_OUT + c);
                float4 a3 = *(const float4*)(u + (size_t)d3 * C_OUT + c);
                m = max4(m, max4(max4(a0, a1), max4(a2, a3)));
            }
            for (; e < end; ++e) {
                int d = edst[e];
                m = max4(m, *(const float4*)(u + (size_t)d * C_OUT + c));
            }
            float4 a = make_float4(0.f, 0.f, 0.f, 0.f);
            if (end > start) {
                float4 vv = *(const float4*)(v + (size_t)n * C_OUT + c);
                a.x = fmaxf(vv.x + m.x, 0.f);
                a.y = fmaxf(vv.y + m.y, 0.f);
                a.z = fmaxf(vv.z + m.z, 0.f);
                a.w = fmaxf(vv.w + m.w, 0.f);
            }
            *(float4*)(out + (size_t)n * C_OUT + c) = a;
            s1x += a.x; s1y += a.y; s1z += a.z; s1w += a.w;
            s2x += a.x * a.x; s2y += a.y * a.y; s2z += a.z * a.z; s2w += a.w * a.w;
        }
    }

    // Block-level stats reduce across the 4 slots, then 8 atomics per lane.
    __shared__ float red[4][64][8];
    red[slot][lane][0] = s1x; red[slot][lane][1] = s1y;
    red[slot][lane][2] = s1z; red[slot][lane][3] = s1w;
    red[slot][lane][4] = s2x; red[slot][lane][5] = s2y;
    red[slot][lane][6] = s2z; red[slot][lane][7] = s2w;
    __syncthreads();
    if (slot == 0) {
        float r[8];
        #pragma unroll
        for (int j = 0; j < 8; ++j)
            r[j] = red[0][lane][j] + red[1][lane][j] + red[2][lane][j] + red[3][lane][j];
        #pragma unroll
        for (int j = 0; j < 4; ++j) {
            atomicAdd(&sums[c + j], r[j]);
            atomicAdd(&sumsq[c + j], r[4 + j]);
        }
    }
}

// ---------------------------------------------------------------------------
// BatchNorm (batch stats, biased var) + ReLU, in place.
// ---------------------------------------------------------------------------
__global__ __launch_bounds__(256) void bn_apply(
    float* __restrict__ out, const float* __restrict__ sums,
    const float* __restrict__ sumsq, const float* __restrict__ gamma,
    const float* __restrict__ beta)
{
    const int idx = blockIdx.x * 256 + threadIdx.x;
    if (idx >= N_NODES * C_OUT) return;
    const int c = idx & (C_OUT - 1);
    const float inv_n = 1.f / (float)N_NODES;
    const float mean = sums[c] * inv_n;
    const float var = sumsq[c] * inv_n - mean * mean;
    const float scale = rsqrtf(var + BN_EPS) * gamma[c];
    float val = (out[idx] - mean) * scale + beta[c];
    out[idx] = fmaxf(val, 0.f);
}

extern "C" void kernel_launch(void* const* d_in, const int* in_sizes, int n_in,
                              void* d_out, int out_size, void* d_ws, size_t ws_size,
                              hipStream_t stream) {
    const float* x     = (const float*)d_in[0];
    const int*   src   = (const int*)d_in[1];
    const int*   dst   = (const int*)d_in[2];
    const float* theta = (const float*)d_in[3];
    const float* phi   = (const float*)d_in[4];
    const float* gamma = (const float*)d_in[5];
    const float* beta  = (const float*)d_in[6];
    float* out = (float*)d_out;

    // Workspace layout (16B-aligned chunks):
    char* ws = (char*)d_ws;
    const size_t uv_elems = (size_t)N_NODES * C_OUT;
    float* u      = (float*)ws;                               // 51.2 MB
    float* v      = u + uv_elems;                             // 51.2 MB
    float* sums   = v + uv_elems;                             // 1 KB
    float* sumsq  = sums + C_OUT;                             // 1 KB
    int*   deg    = (int*)(sumsq + C_OUT);                    // 200 KB (contiguous w/ sums for one memset)
    int*   off    = deg + N_NODES;                            // 200 KB + 4
    int*   cursor = off + N_NODES + 4;                        // 200 KB (pad keeps 16B align)
    int*   edst   = cursor + N_NODES;                         // 3.2 MB

    // Zero sums, sumsq, deg in one shot (they are contiguous).
    hipMemsetAsync(sums, 0, (2 * C_OUT + N_NODES) * sizeof(int), stream);

    dim3 gA((N_NODES + 63) / 64, (2 * C_OUT) / 64);
    gemm_uv<<<gA, 256, 0, stream>>>(x, theta, phi, u, v);

    const int EB = (N_EDGES + 255) / 256;
    hist_src<<<EB, 256, 0, stream>>>(src, deg);
    scan_deg<<<1, 1024, 0, stream>>>(deg, off);
    hipMemcpyAsync(cursor, off, N_NODES * sizeof(int),
                   hipMemcpyDeviceToDevice, stream);
    scatter_edges<<<EB, 256, 0, stream>>>(src, dst, cursor, edst);

    gather_max<<<(N_NODES + NB - 1) / NB, 256, 0, stream>>>(
        off, edst, u, v, out, sums, sumsq);

    bn_apply<<<(N_NODES * C_OUT + 255) / 256, 256, 0, stream>>>(
        out, sums, sumsq, gamma, beta);
}

// Round 3
// 677.828 us; speedup vs baseline: 3.6149x; 1.2384x over previous
//
#include <hip/hip_runtime.h>

#define N_NODES 50000
#define N_EDGES 800000
#define C_IN 128
#define C_OUT 256
#define BN_EPS 1e-5f
#define NBLK ((N_NODES + 255) / 256)   // 196 scan blocks

// fp32 -> bf16 round-to-nearest-even
__device__ __forceinline__ unsigned short f2bf(float f) {
    unsigned int u = __float_as_uint(f);
    u = (u + 0x7fffu + ((u >> 16) & 1u)) >> 16;
    return (unsigned short)u;
}

// ---------------------------------------------------------------------------
// Kernel A: u = bf16(x @ theta^T)        (tiles blockIdx.y 0..3)
//           v = x @ (phi - theta)^T fp32 (tiles blockIdx.y 4..7)
// Identity: theta@(xj-xi) + phi@xi = u[dst] + v[src]; relu/max commute so the
// edge pass only needs max over u rows. u in bf16 halves gather traffic.
// ---------------------------------------------------------------------------
__global__ __launch_bounds__(256) void gemm_uv(
    const float* __restrict__ x,      // [N, 128]
    const float* __restrict__ theta,  // [256, 128]
    const float* __restrict__ phi,    // [256, 128]
    unsigned short* __restrict__ u,   // [N, 256] bf16
    float* __restrict__ v)            // [N, 256] fp32
{
    __shared__ float xs[64][C_IN + 1];
    __shared__ float wsm[64][C_IN + 1];

    const int n0 = blockIdx.x * 64;
    const int c0 = blockIdx.y * 64;  // 0..511, never straddles 256
    const int tid = threadIdx.x;

    #pragma unroll
    for (int i = 0; i < 8; ++i) {
        int f = tid + i * 256;   // 0..2047
        int r = f >> 5;          // 32 float4 per row
        int k4 = f & 31;
        float4 val = make_float4(0.f, 0.f, 0.f, 0.f);
        int n = n0 + r;
        if (n < N_NODES) val = *(const float4*)(x + (size_t)n * C_IN + k4 * 4);
        xs[r][k4 * 4 + 0] = val.x;
        xs[r][k4 * 4 + 1] = val.y;
        xs[r][k4 * 4 + 2] = val.z;
        xs[r][k4 * 4 + 3] = val.w;
    }
    const bool is_phi = (c0 >= C_OUT);
    const int cb = is_phi ? (c0 - C_OUT) : c0;
    #pragma unroll
    for (int i = 0; i < 8; ++i) {
        int f = tid + i * 256;
        int r = f >> 5;
        int k4 = f & 31;
        float4 tv = *(const float4*)(theta + (size_t)(cb + r) * C_IN + k4 * 4);
        float4 val = tv;
        if (is_phi) {
            float4 pv = *(const float4*)(phi + (size_t)(cb + r) * C_IN + k4 * 4);
            val = make_float4(pv.x - tv.x, pv.y - tv.y, pv.z - tv.z, pv.w - tv.w);
        }
        wsm[r][k4 * 4 + 0] = val.x;
        wsm[r][k4 * 4 + 1] = val.y;
        wsm[r][k4 * 4 + 2] = val.z;
        wsm[r][k4 * 4 + 3] = val.w;
    }
    __syncthreads();

    const int tr = tid & 15;
    const int tc = tid >> 4;
    float acc[4][4];
    #pragma unroll
    for (int i = 0; i < 4; ++i)
        #pragma unroll
        for (int j = 0; j < 4; ++j) acc[i][j] = 0.f;

    for (int k = 0; k < C_IN; ++k) {
        float a[4], b[4];
        #pragma unroll
        for (int i = 0; i < 4; ++i) a[i] = xs[tr * 4 + i][k];
        #pragma unroll
        for (int j = 0; j < 4; ++j) b[j] = wsm[tc * 4 + j][k];
        #pragma unroll
        for (int i = 0; i < 4; ++i)
            #pragma unroll
            for (int j = 0; j < 4; ++j)
                acc[i][j] = fmaf(a[i], b[j], acc[i][j]);
    }

    #pragma unroll
    for (int i = 0; i < 4; ++i) {
        int n = n0 + tr * 4 + i;
        if (n >= N_NODES) continue;
        if (!is_phi) {
            ushort4 p = make_ushort4(f2bf(acc[i][0]), f2bf(acc[i][1]),
                                     f2bf(acc[i][2]), f2bf(acc[i][3]));
            *(ushort4*)(u + (size_t)n * C_OUT + c0 + tc * 4) = p;
        } else {
            #pragma unroll
            for (int j = 0; j < 4; ++j)
                v[(size_t)n * C_OUT + (c0 - C_OUT) + tc * 4 + j] = acc[i][j];
        }
    }
}

// ---------------------------------------------------------------------------
// CSR build: histogram -> 3-phase multi-block exclusive scan -> scatter.
// ---------------------------------------------------------------------------
__global__ __launch_bounds__(256) void hist_src(
    const int* __restrict__ src, int* __restrict__ deg)
{
    int i = blockIdx.x * 256 + threadIdx.x;
    if (i < N_EDGES) atomicAdd(&deg[src[i]], 1);
}

__global__ __launch_bounds__(256) void scan_part(
    const int* __restrict__ deg, int* __restrict__ partials)
{
    __shared__ int s[256];
    const int tid = threadIdx.x;
    int i = blockIdx.x * 256 + tid;
    s[tid] = (i < N_NODES) ? deg[i] : 0;
    __syncthreads();
    for (int d = 128; d > 0; d >>= 1) {
        if (tid < d) s[tid] += s[tid + d];
        __syncthreads();
    }
    if (tid == 0) partials[blockIdx.x] = s[0];
}

__global__ __launch_bounds__(256) void scan_mid(
    int* __restrict__ partials, int* __restrict__ off)
{
    __shared__ int s[256];
    const int tid = threadIdx.x;
    int v = (tid < NBLK) ? partials[tid] : 0;
    s[tid] = v;
    __syncthreads();
    for (int d = 1; d < 256; d <<= 1) {
        int t = (tid >= d) ? s[tid - d] : 0;
        __syncthreads();
        s[tid] += t;
        __syncthreads();
    }
    if (tid < NBLK) partials[tid] = s[tid] - v;   // exclusive block prefix
    if (tid == NBLK - 1) off[N_NODES] = s[tid];   // total = E
}

__global__ __launch_bounds__(256) void scan_fin(
    const int* __restrict__ deg, const int* __restrict__ partials,
    int* __restrict__ off, int* __restrict__ cursor)
{
    __shared__ int s[256];
    const int tid = threadIdx.x;
    int i = blockIdx.x * 256 + tid;
    int v = (i < N_NODES) ? deg[i] : 0;
    s[tid] = v;
    __syncthreads();
    for (int d = 1; d < 256; d <<= 1) {
        int t = (tid >= d) ? s[tid - d] : 0;
        __syncthreads();
        s[tid] += t;
        __syncthreads();
    }
    int ex = s[tid] - v + partials[blockIdx.x];
    if (i < N_NODES) { off[i] = ex; cursor[i] = ex; }
}

__global__ __launch_bounds__(256) void scatter_edges(
    const int* __restrict__ src, const int* __restrict__ dst,
    int* __restrict__ cursor, int* __restrict__ edst)
{
    int i = blockIdx.x * 256 + threadIdx.x;
    if (i < N_EDGES) {
        int pos = atomicAdd(&cursor[src[i]], 1);
        edst[pos] = dst[i];
    }
}

// ---------------------------------------------------------------------------
// Gather-max over bf16 u rows + v-add + relu + per-channel stats.
// One 64-lane group per node (lane = 4 channels, uint2 = 8B of bf16).
// 8-deep edge groups with clamped tail indices (dup reads harmless for max)
// so every group is one fully-parallel latency window.
// ---------------------------------------------------------------------------
#define NB 16

__device__ __forceinline__ float4 bfrow(const unsigned short* __restrict__ u,
                                        int d, int c) {
    uint2 w = *(const uint2*)(u + (size_t)d * C_OUT + c);
    return make_float4(__uint_as_float(w.x << 16),
                       __uint_as_float(w.x & 0xFFFF0000u),
                       __uint_as_float(w.y << 16),
                       __uint_as_float(w.y & 0xFFFF0000u));
}

__device__ __forceinline__ float4 max4(float4 a, float4 b) {
    return make_float4(fmaxf(a.x, b.x), fmaxf(a.y, b.y),
                       fmaxf(a.z, b.z), fmaxf(a.w, b.w));
}

__global__ __launch_bounds__(256) void gather_max(
    const int* __restrict__ off, const int* __restrict__ edst,
    const unsigned short* __restrict__ u, const float* __restrict__ v,
    float* __restrict__ out, float* __restrict__ sums, float* __restrict__ sumsq)
{
    const int slot = threadIdx.x >> 6;   // wave id: 4 concurrent nodes
    const int lane = threadIdx.x & 63;   // channel group
    const int c = lane * 4;

    float s1x = 0.f, s1y = 0.f, s1z = 0.f, s1w = 0.f;
    float s2x = 0.f, s2y = 0.f, s2z = 0.f, s2w = 0.f;

    const int n_base = blockIdx.x * NB;
    for (int it = 0; it < NB / 4; ++it) {
        int n = n_base + it * 4 + slot;
        if (n < N_NODES) {
            const int start = off[n];
            const int end = off[n + 1];
            float4 a = make_float4(0.f, 0.f, 0.f, 0.f);
            if (end > start) {
                float4 m = make_float4(-INFINITY, -INFINITY, -INFINITY, -INFINITY);
                const int lim = end - 1;
                for (int base = start; base < end; base += 8) {
                    int i1 = min(base + 1, lim), i2 = min(base + 2, lim);
                    int i3 = min(base + 3, lim), i4 = min(base + 4, lim);
                    int i5 = min(base + 5, lim), i6 = min(base + 6, lim);
                    int i7 = min(base + 7, lim);
                    int d0 = edst[base], d1 = edst[i1], d2 = edst[i2], d3 = edst[i3];
                    int d4 = edst[i4], d5 = edst[i5], d6 = edst[i6], d7 = edst[i7];
                    float4 a0 = bfrow(u, d0, c), a1 = bfrow(u, d1, c);
                    float4 a2 = bfrow(u, d2, c), a3 = bfrow(u, d3, c);
                    float4 a4 = bfrow(u, d4, c), a5 = bfrow(u, d5, c);
                    float4 a6 = bfrow(u, d6, c), a7 = bfrow(u, d7, c);
                    m = max4(m, max4(max4(max4(a0, a1), max4(a2, a3)),
                                     max4(max4(a4, a5), max4(a6, a7))));
                }
                float4 vv = *(const float4*)(v + (size_t)n * C_OUT + c);
                a.x = fmaxf(vv.x + m.x, 0.f);
                a.y = fmaxf(vv.y + m.y, 0.f);
                a.z = fmaxf(vv.z + m.z, 0.f);
                a.w = fmaxf(vv.w + m.w, 0.f);
            }
            *(float4*)(out + (size_t)n * C_OUT + c) = a;
            s1x += a.x; s1y += a.y; s1z += a.z; s1w += a.w;
            s2x += a.x * a.x; s2y += a.y * a.y; s2z += a.z * a.z; s2w += a.w * a.w;
        }
    }

    __shared__ float red[4][64][8];
    red[slot][lane][0] = s1x; red[slot][lane][1] = s1y;
    red[slot][lane][2] = s1z; red[slot][lane][3] = s1w;
    red[slot][lane][4] = s2x; red[slot][lane][5] = s2y;
    red[slot][lane][6] = s2z; red[slot][lane][7] = s2w;
    __syncthreads();
    if (slot == 0) {
        float r[8];
        #pragma unroll
        for (int j = 0; j < 8; ++j)
            r[j] = red[0][lane][j] + red[1][lane][j] + red[2][lane][j] + red[3][lane][j];
        #pragma unroll
        for (int j = 0; j < 4; ++j) {
            atomicAdd(&sums[c + j], r[j]);
            atomicAdd(&sumsq[c + j], r[4 + j]);
        }
    }
}

// ---------------------------------------------------------------------------
// BatchNorm (batch stats, biased var) + ReLU, in place.
// ---------------------------------------------------------------------------
__global__ __launch_bounds__(256) void bn_apply(
    float* __restrict__ out, const float* __restrict__ sums,
    const float* __restrict__ sumsq, const float* __restrict__ gamma,
    const float* __restrict__ beta)
{
    const int idx = blockIdx.x * 256 + threadIdx.x;
    if (idx >= N_NODES * C_OUT) return;
    const int c = idx & (C_OUT - 1);
    const float inv_n = 1.f / (float)N_NODES;
    const float mean = sums[c] * inv_n;
    const float var = sumsq[c] * inv_n - mean * mean;
    const float scale = rsqrtf(var + BN_EPS) * gamma[c];
    float val = (out[idx] - mean) * scale + beta[c];
    out[idx] = fmaxf(val, 0.f);
}

extern "C" void kernel_launch(void* const* d_in, const int* in_sizes, int n_in,
                              void* d_out, int out_size, void* d_ws, size_t ws_size,
                              hipStream_t stream) {
    const float* x     = (const float*)d_in[0];
    const int*   src   = (const int*)d_in[1];
    const int*   dst   = (const int*)d_in[2];
    const float* theta = (const float*)d_in[3];
    const float* phi   = (const float*)d_in[4];
    const float* gamma = (const float*)d_in[5];
    const float* beta  = (const float*)d_in[6];
    float* out = (float*)d_out;

    // Workspace layout (16B-aligned chunks):
    char* ws = (char*)d_ws;
    const size_t uv_elems = (size_t)N_NODES * C_OUT;
    unsigned short* u = (unsigned short*)ws;                  // 25.6 MB bf16
    float* v      = (float*)(ws + uv_elems * sizeof(unsigned short)); // 51.2 MB
    float* sums   = v + uv_elems;
    float* sumsq  = sums + C_OUT;
    int*   deg    = (int*)(sumsq + C_OUT);                    // contiguous w/ sums for one memset
    int*   off    = deg + N_NODES;                            // N_NODES+1 entries
    int*   cursor = off + N_NODES + 4;                        // pad keeps 16B align
    int*   edst   = cursor + N_NODES;                         // 3.2 MB
    int*   partials = edst + N_EDGES;                         // NBLK ints

    // Zero sums, sumsq, deg in one shot (they are contiguous).
    hipMemsetAsync(sums, 0, (2 * C_OUT + N_NODES) * sizeof(int), stream);

    dim3 gA((N_NODES + 63) / 64, (2 * C_OUT) / 64);
    gemm_uv<<<gA, 256, 0, stream>>>(x, theta, phi, u, v);

    const int EB = (N_EDGES + 255) / 256;
    hist_src<<<EB, 256, 0, stream>>>(src, deg);
    scan_part<<<NBLK, 256, 0, stream>>>(deg, partials);
    scan_mid<<<1, 256, 0, stream>>>(partials, off);
    scan_fin<<<NBLK, 256, 0, stream>>>(deg, partials, off, cursor);
    scatter_edges<<<EB, 256, 0, stream>>>(src, dst, cursor, edst);

    gather_max<<<(N_NODES + NB - 1) / NB, 256, 0, stream>>>(
        off, edst, u, v, out, sums, sumsq);

    bn_apply<<<(N_NODES * C_OUT + 255) / 256, 256, 0, stream>>>(
        out, sums, sumsq, gamma, beta);
}

// Round 4
// 497.112 us; speedup vs baseline: 4.9291x; 1.3635x over previous
//
#include <hip/hip_runtime.h>

#define N_NODES 50000
#define N_EDGES 800000
#define C_IN 128
#define C_OUT 256
#define BN_EPS 1e-5f
#define NBLK ((N_NODES + 255) / 256)   // 196 scan blocks
#define SL 8                           // channel slices (== XCD count)
#define SLC 32                         // channels per slice
#define NPB 64                         // nodes per gather block

// fp32 -> bf16 round-to-nearest-even
__device__ __forceinline__ unsigned short f2bf(float f) {
    unsigned int u = __float_as_uint(f);
    u = (u + 0x7fffu + ((u >> 16) & 1u)) >> 16;
    return (unsigned short)u;
}

// ---------------------------------------------------------------------------
// Kernel A: u = bf16(x @ theta^T), v = x @ (phi - theta)^T (fp32).
// Identity: theta@(xj-xi) + phi@xi = u[dst] + v[src]; relu/max commute so the
// edge pass only needs max over u rows.
// u and v are stored SLICE-MAJOR: [SL][N_NODES][SLC] so that one channel
// slice (3.2 MB bf16) fits a single XCD's 4 MiB L2 during the gather.
// ---------------------------------------------------------------------------
__global__ __launch_bounds__(256) void gemm_uv(
    const float* __restrict__ x,      // [N, 128]
    const float* __restrict__ theta,  // [256, 128]
    const float* __restrict__ phi,    // [256, 128]
    unsigned short* __restrict__ u,   // [SL][N][SLC] bf16
    float* __restrict__ v)            // [SL][N][SLC] fp32
{
    __shared__ float xs[64][C_IN + 1];
    __shared__ float wsm[64][C_IN + 1];

    const int n0 = blockIdx.x * 64;
    const int c0 = blockIdx.y * 64;  // 0..511, never straddles 256
    const int tid = threadIdx.x;

    #pragma unroll
    for (int i = 0; i < 8; ++i) {
        int f = tid + i * 256;   // 0..2047
        int r = f >> 5;          // 32 float4 per row
        int k4 = f & 31;
        float4 val = make_float4(0.f, 0.f, 0.f, 0.f);
        int n = n0 + r;
        if (n < N_NODES) val = *(const float4*)(x + (size_t)n * C_IN + k4 * 4);
        xs[r][k4 * 4 + 0] = val.x;
        xs[r][k4 * 4 + 1] = val.y;
        xs[r][k4 * 4 + 2] = val.z;
        xs[r][k4 * 4 + 3] = val.w;
    }
    const bool is_phi = (c0 >= C_OUT);
    const int cb = is_phi ? (c0 - C_OUT) : c0;
    #pragma unroll
    for (int i = 0; i < 8; ++i) {
        int f = tid + i * 256;
        int r = f >> 5;
        int k4 = f & 31;
        float4 tv = *(const float4*)(theta + (size_t)(cb + r) * C_IN + k4 * 4);
        float4 val = tv;
        if (is_phi) {
            float4 pv = *(const float4*)(phi + (size_t)(cb + r) * C_IN + k4 * 4);
            val = make_float4(pv.x - tv.x, pv.y - tv.y, pv.z - tv.z, pv.w - tv.w);
        }
        wsm[r][k4 * 4 + 0] = val.x;
        wsm[r][k4 * 4 + 1] = val.y;
        wsm[r][k4 * 4 + 2] = val.z;
        wsm[r][k4 * 4 + 3] = val.w;
    }
    __syncthreads();

    const int tr = tid & 15;
    const int tc = tid >> 4;
    float acc[4][4];
    #pragma unroll
    for (int i = 0; i < 4; ++i)
        #pragma unroll
        for (int j = 0; j < 4; ++j) acc[i][j] = 0.f;

    for (int k = 0; k < C_IN; ++k) {
        float a[4], b[4];
        #pragma unroll
        for (int i = 0; i < 4; ++i) a[i] = xs[tr * 4 + i][k];
        #pragma unroll
        for (int j = 0; j < 4; ++j) b[j] = wsm[tc * 4 + j][k];
        #pragma unroll
        for (int i = 0; i < 4; ++i)
            #pragma unroll
            for (int j = 0; j < 4; ++j)
                acc[i][j] = fmaf(a[i], b[j], acc[i][j]);
    }

    #pragma unroll
    for (int i = 0; i < 4; ++i) {
        int n = n0 + tr * 4 + i;
        if (n >= N_NODES) continue;
        if (!is_phi) {
            int ch = c0 + tc * 4;            // aligned 4, never crosses 32
            int s = ch >> 5, o = ch & 31;
            ushort4 p = make_ushort4(f2bf(acc[i][0]), f2bf(acc[i][1]),
                                     f2bf(acc[i][2]), f2bf(acc[i][3]));
            *(ushort4*)(u + ((size_t)s * N_NODES + n) * SLC + o) = p;
        } else {
            int ch = (c0 - C_OUT) + tc * 4;
            int s = ch >> 5, o = ch & 31;
            float4 p = make_float4(acc[i][0], acc[i][1], acc[i][2], acc[i][3]);
            *(float4*)(v + ((size_t)s * N_NODES + n) * SLC + o) = p;
        }
    }
}

// ---------------------------------------------------------------------------
// CSR build: histogram -> 3-phase multi-block exclusive scan -> scatter.
// ---------------------------------------------------------------------------
__global__ __launch_bounds__(256) void hist_src(
    const int* __restrict__ src, int* __restrict__ deg)
{
    int i = blockIdx.x * 256 + threadIdx.x;
    if (i < N_EDGES) atomicAdd(&deg[src[i]], 1);
}

__global__ __launch_bounds__(256) void scan_part(
    const int* __restrict__ deg, int* __restrict__ partials)
{
    __shared__ int s[256];
    const int tid = threadIdx.x;
    int i = blockIdx.x * 256 + tid;
    s[tid] = (i < N_NODES) ? deg[i] : 0;
    __syncthreads();
    for (int d = 128; d > 0; d >>= 1) {
        if (tid < d) s[tid] += s[tid + d];
        __syncthreads();
    }
    if (tid == 0) partials[blockIdx.x] = s[0];
}

__global__ __launch_bounds__(256) void scan_mid(
    int* __restrict__ partials, int* __restrict__ off)
{
    __shared__ int s[256];
    const int tid = threadIdx.x;
    int v = (tid < NBLK) ? partials[tid] : 0;
    s[tid] = v;
    __syncthreads();
    for (int d = 1; d < 256; d <<= 1) {
        int t = (tid >= d) ? s[tid - d] : 0;
        __syncthreads();
        s[tid] += t;
        __syncthreads();
    }
    if (tid < NBLK) partials[tid] = s[tid] - v;   // exclusive block prefix
    if (tid == NBLK - 1) off[N_NODES] = s[tid];   // total = E
}

__global__ __launch_bounds__(256) void scan_fin(
    const int* __restrict__ deg, const int* __restrict__ partials,
    int* __restrict__ off, int* __restrict__ cursor)
{
    __shared__ int s[256];
    const int tid = threadIdx.x;
    int i = blockIdx.x * 256 + tid;
    int v = (i < N_NODES) ? deg[i] : 0;
    s[tid] = v;
    __syncthreads();
    for (int d = 1; d < 256; d <<= 1) {
        int t = (tid >= d) ? s[tid - d] : 0;
        __syncthreads();
        s[tid] += t;
        __syncthreads();
    }
    int ex = s[tid] - v + partials[blockIdx.x];
    if (i < N_NODES) { off[i] = ex; cursor[i] = ex; }
}

__global__ __launch_bounds__(256) void scatter_edges(
    const int* __restrict__ src, const int* __restrict__ dst,
    int* __restrict__ cursor, int* __restrict__ edst)
{
    int i = blockIdx.x * 256 + threadIdx.x;
    if (i < N_EDGES) {
        int pos = atomicAdd(&cursor[src[i]], 1);
        edst[pos] = dst[i];
    }
}

// ---------------------------------------------------------------------------
// Sliced gather-max. blockIdx & 7 = channel slice = XCD (round-robin dispatch
// heuristic): XCD s only ever touches u-slice s (3.2 MB, L2-resident) so the
// 16x row reuse is served by its own L2. One edge-slice read = 1 cache line.
// Wave: 4 edge-groups x 16 lanes; lane = 2 channels (1 dword of bf16x2).
// Two independent u loads in flight per iteration (8 edges/iter, clamped
// tail dups are harmless under max).
// ---------------------------------------------------------------------------
__device__ __forceinline__ float bflo(unsigned int w) {
    return __uint_as_float(w << 16);
}
__device__ __forceinline__ float bfhi(unsigned int w) {
    return __uint_as_float(w & 0xFFFF0000u);
}

__global__ __launch_bounds__(256) void gather_slice(
    const int* __restrict__ off, const int* __restrict__ edst,
    const unsigned short* __restrict__ u, const float* __restrict__ v,
    float* __restrict__ out, float* __restrict__ sums, float* __restrict__ sumsq)
{
    const int slice = blockIdx.x & 7;
    const int chunk = blockIdx.x >> 3;
    const int wave = threadIdx.x >> 6;
    const int lane = threadIdx.x & 63;
    const int g = lane >> 4;      // edge group 0..3
    const int l16 = lane & 15;    // channel-pair index within slice

    const unsigned short* ubase = u + (size_t)slice * N_NODES * SLC;
    const float* vbase = v + (size_t)slice * N_NODES * SLC;

    float s1_0 = 0.f, s1_1 = 0.f, s2_0 = 0.f, s2_1 = 0.f;

    for (int i = 0; i < NPB / 4; ++i) {
        const int n = chunk * NPB + wave * (NPB / 4) + i;
        if (n >= N_NODES) break;
        const int start = off[n];
        const int end = off[n + 1];
        float a0 = 0.f, a1 = 0.f;
        if (end > start) {
            float m0 = -INFINITY, m1 = -INFINITY;
            const int lim = end - 1;
            for (int e = start; e < end; e += 8) {
                int iA = min(e + g, lim);
                int iB = min(e + 4 + g, lim);
                int dA = edst[iA];                 // broadcast within group
                int dB = edst[iB];
                unsigned int wA = *(const unsigned int*)(ubase + (size_t)dA * SLC + l16 * 2);
                unsigned int wB = *(const unsigned int*)(ubase + (size_t)dB * SLC + l16 * 2);
                m0 = fmaxf(m0, fmaxf(bflo(wA), bflo(wB)));
                m1 = fmaxf(m1, fmaxf(bfhi(wA), bfhi(wB)));
            }
            // combine the 4 edge groups (lanes xor 16, xor 32)
            m0 = fmaxf(m0, __shfl_xor(m0, 16));
            m0 = fmaxf(m0, __shfl_xor(m0, 32));
            m1 = fmaxf(m1, __shfl_xor(m1, 16));
            m1 = fmaxf(m1, __shfl_xor(m1, 32));
            float2 vv = *(const float2*)(vbase + (size_t)n * SLC + l16 * 2);
            a0 = fmaxf(vv.x + m0, 0.f);
            a1 = fmaxf(vv.y + m1, 0.f);
        }
        if (g == 0) {
            *(float2*)(out + (size_t)n * C_OUT + slice * SLC + l16 * 2) =
                make_float2(a0, a1);
            s1_0 += a0; s1_1 += a1;
            s2_0 += a0 * a0; s2_1 += a1 * a1;
        }
    }

    // Block stats: g==0 lanes of each wave hold partials for 16 ch-pairs.
    __shared__ float red[4][16][4];
    if (g == 0) {
        red[wave][l16][0] = s1_0; red[wave][l16][1] = s1_1;
        red[wave][l16][2] = s2_0; red[wave][l16][3] = s2_1;
    }
    __syncthreads();
    if (threadIdx.x < 16) {
        const int t = threadIdx.x;
        float r0 = 0.f, r1 = 0.f, r2 = 0.f, r3 = 0.f;
        #pragma unroll
        for (int w = 0; w < 4; ++w) {
            r0 += red[w][t][0]; r1 += red[w][t][1];
            r2 += red[w][t][2]; r3 += red[w][t][3];
        }
        const int c = slice * SLC + t * 2;
        atomicAdd(&sums[c + 0], r0);
        atomicAdd(&sums[c + 1], r1);
        atomicAdd(&sumsq[c + 0], r2);
        atomicAdd(&sumsq[c + 1], r3);
    }
}

// ---------------------------------------------------------------------------
// BatchNorm (batch stats, biased var) + ReLU, in place.
// ---------------------------------------------------------------------------
__global__ __launch_bounds__(256) void bn_apply(
    float* __restrict__ out, const float* __restrict__ sums,
    const float* __restrict__ sumsq, const float* __restrict__ gamma,
    const float* __restrict__ beta)
{
    const int idx = blockIdx.x * 256 + threadIdx.x;
    if (idx >= N_NODES * C_OUT) return;
    const int c = idx & (C_OUT - 1);
    const float inv_n = 1.f / (float)N_NODES;
    const float mean = sums[c] * inv_n;
    const float var = sumsq[c] * inv_n - mean * mean;
    const float scale = rsqrtf(var + BN_EPS) * gamma[c];
    float val = (out[idx] - mean) * scale + beta[c];
    out[idx] = fmaxf(val, 0.f);
}

extern "C" void kernel_launch(void* const* d_in, const int* in_sizes, int n_in,
                              void* d_out, int out_size, void* d_ws, size_t ws_size,
                              hipStream_t stream) {
    const float* x     = (const float*)d_in[0];
    const int*   src   = (const int*)d_in[1];
    const int*   dst   = (const int*)d_in[2];
    const float* theta = (const float*)d_in[3];
    const float* phi   = (const float*)d_in[4];
    const float* gamma = (const float*)d_in[5];
    const float* beta  = (const float*)d_in[6];
    float* out = (float*)d_out;

    // Workspace layout (16B-aligned chunks):
    char* ws = (char*)d_ws;
    const size_t uv_elems = (size_t)N_NODES * C_OUT;
    unsigned short* u = (unsigned short*)ws;                  // 25.6 MB bf16 slice-major
    float* v      = (float*)(ws + uv_elems * sizeof(unsigned short)); // 51.2 MB slice-major
    float* sums   = v + uv_elems;
    float* sumsq  = sums + C_OUT;
    int*   deg    = (int*)(sumsq + C_OUT);                    // contiguous w/ sums for one memset
    int*   off    = deg + N_NODES;                            // N_NODES+1 entries
    int*   cursor = off + N_NODES + 4;                        // pad keeps 16B align
    int*   edst   = cursor + N_NODES;                         // 3.2 MB
    int*   partials = edst + N_EDGES;                         // NBLK ints

    // Zero sums, sumsq, deg in one shot (they are contiguous).
    hipMemsetAsync(sums, 0, (2 * C_OUT + N_NODES) * sizeof(int), stream);

    dim3 gA((N_NODES + 63) / 64, (2 * C_OUT) / 64);
    gemm_uv<<<gA, 256, 0, stream>>>(x, theta, phi, u, v);

    const int EB = (N_EDGES + 255) / 256;
    hist_src<<<EB, 256, 0, stream>>>(src, deg);
    scan_part<<<NBLK, 256, 0, stream>>>(deg, partials);
    scan_mid<<<1, 256, 0, stream>>>(partials, off);
    scan_fin<<<NBLK, 256, 0, stream>>>(deg, partials, off, cursor);
    scatter_edges<<<EB, 256, 0, stream>>>(src, dst, cursor, edst);

    const int chunks = (N_NODES + NPB - 1) / NPB;
    gather_slice<<<chunks * SL, 256, 0, stream>>>(
        off, edst, u, v, out, sums, sumsq);

    bn_apply<<<(N_NODES * C_OUT + 255) / 256, 256, 0, stream>>>(
        out, sums, sumsq, gamma, beta);
}

// Round 5
// 386.371 us; speedup vs baseline: 6.3418x; 1.2866x over previous
//
#include <hip/hip_runtime.h>

#define N_NODES 50000
#define N_EDGES 800000
#define C_IN 128
#define C_OUT 256
#define BN_EPS 1e-5f
#define NBLK ((N_NODES + 255) / 256)   // 196 scan blocks
#define SL 8                           // channel slices (== XCD count)
#define SLC 32                         // channels per slice
#define NPB 64                         // nodes per gather block
#define PAD 8                          // LDS row pad (bf16 elems, keeps 16B align)

using short8  = __attribute__((ext_vector_type(8))) short;
using floatx4 = __attribute__((ext_vector_type(4))) float;

// fp32 -> bf16 round-to-nearest-even
__device__ __forceinline__ unsigned short f2bf(float f) {
    unsigned int u = __float_as_uint(f);
    u = (u + 0x7fffu + ((u >> 16) & 1u)) >> 16;
    return (unsigned short)u;
}

// ---------------------------------------------------------------------------
// Converts: x -> bf16 [N,128]; W' = [theta ; phi-theta] -> bf16 [512,128].
// Identity: theta@(xj-xi) + phi@xi = u[dst] + v[src]; relu/max commute so the
// edge pass only needs max over u rows.
// ---------------------------------------------------------------------------
__global__ __launch_bounds__(256) void convert_x(
    const float* __restrict__ x, unsigned short* __restrict__ xb)
{
    int i = blockIdx.x * 256 + threadIdx.x;
    if (i < N_NODES * C_IN / 4) {
        float4 vv = ((const float4*)x)[i];
        ((ushort4*)xb)[i] = make_ushort4(f2bf(vv.x), f2bf(vv.y),
                                         f2bf(vv.z), f2bf(vv.w));
    }
}

__global__ __launch_bounds__(256) void convert_w(
    const float* __restrict__ theta, const float* __restrict__ phi,
    unsigned short* __restrict__ wb)
{
    int i = blockIdx.x * 256 + threadIdx.x;       // float4 index over [512][128]
    if (i >= 512 * C_IN / 4) return;
    float4 t;
    if (i < 256 * C_IN / 4) {
        t = ((const float4*)theta)[i];
    } else {
        int j = i - 256 * C_IN / 4;
        float4 th = ((const float4*)theta)[j];
        float4 ph = ((const float4*)phi)[j];
        t = make_float4(ph.x - th.x, ph.y - th.y, ph.z - th.z, ph.w - th.w);
    }
    ((ushort4*)wb)[i] = make_ushort4(f2bf(t.x), f2bf(t.y), f2bf(t.z), f2bf(t.w));
}

// ---------------------------------------------------------------------------
// MFMA GEMM: out[n][c] = xb[n][:] . wb[c][:], M=50000, N=512, K=128.
// Block tile 128(M) x 64(N), K fully staged. 4 waves, each 32x64 =
// 2x4 16x16 tiles x 4 K-steps. Outputs go straight to slice-major u (bf16,
// c<256) / v (fp32, c>=256) for the XCD-local gather.
// Verified layouts: A-frag A[m=lane&15][k=quad*8+j]; B-frag B[k][n=lane&15];
// C/D col=lane&15, row=quad*4+reg (learn_hip m89/m91).
// ---------------------------------------------------------------------------
__global__ __launch_bounds__(256) void gemm_mfma(
    const unsigned short* __restrict__ xb,   // [N,128] bf16
    const unsigned short* __restrict__ wb,   // [512,128] bf16
    unsigned short* __restrict__ u,          // [SL][N][SLC] bf16
    float* __restrict__ v)                   // [SL][N][SLC] fp32
{
    __shared__ unsigned short As[128][C_IN + PAD];
    __shared__ unsigned short Bs[64][C_IN + PAD];
    const int tid = threadIdx.x;

    // Stage A: 128 rows x 128 bf16 (2 threads/row, 8 uint4 each).
    {
        int r = tid >> 1;
        int cb = (tid & 1) * 64;
        int n = blockIdx.x * 128 + r;
        if (n < N_NODES) {
            const uint4* sp = (const uint4*)(xb + (size_t)n * C_IN + cb);
            #pragma unroll
            for (int i = 0; i < 8; ++i) *(uint4*)&As[r][cb + i * 8] = sp[i];
        } else {
            uint4 z = make_uint4(0, 0, 0, 0);
            #pragma unroll
            for (int i = 0; i < 8; ++i) *(uint4*)&As[r][cb + i * 8] = z;
        }
    }
    // Stage B: 64 rows x 128 bf16 (4 threads/row, 4 uint4 each).
    {
        int r = tid >> 2;
        int cb = (tid & 3) * 32;
        const uint4* sp = (const uint4*)(wb + (size_t)(blockIdx.y * 64 + r) * C_IN + cb);
        #pragma unroll
        for (int i = 0; i < 4; ++i) *(uint4*)&Bs[r][cb + i * 8] = sp[i];
    }
    __syncthreads();

    const int wave = tid >> 6;
    const int lane = tid & 63;
    const int l15 = lane & 15;
    const int quad = lane >> 4;

    floatx4 acc[2][4];
    #pragma unroll
    for (int mi = 0; mi < 2; ++mi)
        #pragma unroll
        for (int ni = 0; ni < 4; ++ni)
            acc[mi][ni] = (floatx4){0.f, 0.f, 0.f, 0.f};

    #pragma unroll
    for (int ks = 0; ks < 4; ++ks) {
        short8 a[2], b[4];
        #pragma unroll
        for (int mi = 0; mi < 2; ++mi)
            a[mi] = *(const short8*)&As[wave * 32 + mi * 16 + l15][ks * 32 + quad * 8];
        #pragma unroll
        for (int ni = 0; ni < 4; ++ni)
            b[ni] = *(const short8*)&Bs[ni * 16 + l15][ks * 32 + quad * 8];
        #pragma unroll
        for (int mi = 0; mi < 2; ++mi)
            #pragma unroll
            for (int ni = 0; ni < 4; ++ni)
                acc[mi][ni] = __builtin_amdgcn_mfma_f32_16x16x32_bf16(
                    a[mi], b[ni], acc[mi][ni], 0, 0, 0);
    }

    const bool is_u = (blockIdx.y < 4);   // uniform per block
    #pragma unroll
    for (int mi = 0; mi < 2; ++mi) {
        #pragma unroll
        for (int r = 0; r < 4; ++r) {
            int n = blockIdx.x * 128 + wave * 32 + mi * 16 + quad * 4 + r;
            if (n >= N_NODES) continue;
            #pragma unroll
            for (int ni = 0; ni < 4; ++ni) {
                int c = blockIdx.y * 64 + ni * 16 + l15;   // 0..511
                float val = acc[mi][ni][r];
                if (is_u) {
                    int s = c >> 5, o = c & 31;
                    u[((size_t)s * N_NODES + n) * SLC + o] = f2bf(val);
                } else {
                    int c2 = c - C_OUT;
                    int s = c2 >> 5, o = c2 & 31;
                    v[((size_t)s * N_NODES + n) * SLC + o] = val;
                }
            }
        }
    }
}

// ---------------------------------------------------------------------------
// CSR build: histogram -> 3-phase multi-block exclusive scan -> scatter.
// ---------------------------------------------------------------------------
__global__ __launch_bounds__(256) void hist_src(
    const int* __restrict__ src, int* __restrict__ deg)
{
    int i = blockIdx.x * 256 + threadIdx.x;
    if (i < N_EDGES) atomicAdd(&deg[src[i]], 1);
}

__global__ __launch_bounds__(256) void scan_part(
    const int* __restrict__ deg, int* __restrict__ partials)
{
    __shared__ int s[256];
    const int tid = threadIdx.x;
    int i = blockIdx.x * 256 + tid;
    s[tid] = (i < N_NODES) ? deg[i] : 0;
    __syncthreads();
    for (int d = 128; d > 0; d >>= 1) {
        if (tid < d) s[tid] += s[tid + d];
        __syncthreads();
    }
    if (tid == 0) partials[blockIdx.x] = s[0];
}

__global__ __launch_bounds__(256) void scan_mid(
    int* __restrict__ partials, int* __restrict__ off)
{
    __shared__ int s[256];
    const int tid = threadIdx.x;
    int v = (tid < NBLK) ? partials[tid] : 0;
    s[tid] = v;
    __syncthreads();
    for (int d = 1; d < 256; d <<= 1) {
        int t = (tid >= d) ? s[tid - d] : 0;
        __syncthreads();
        s[tid] += t;
        __syncthreads();
    }
    if (tid < NBLK) partials[tid] = s[tid] - v;   // exclusive block prefix
    if (tid == NBLK - 1) off[N_NODES] = s[tid];   // total = E
}

__global__ __launch_bounds__(256) void scan_fin(
    const int* __restrict__ deg, const int* __restrict__ partials,
    int* __restrict__ off, int* __restrict__ cursor)
{
    __shared__ int s[256];
    const int tid = threadIdx.x;
    int i = blockIdx.x * 256 + tid;
    int v = (i < N_NODES) ? deg[i] : 0;
    s[tid] = v;
    __syncthreads();
    for (int d = 1; d < 256; d <<= 1) {
        int t = (tid >= d) ? s[tid - d] : 0;
        __syncthreads();
        s[tid] += t;
        __syncthreads();
    }
    int ex = s[tid] - v + partials[blockIdx.x];
    if (i < N_NODES) { off[i] = ex; cursor[i] = ex; }
}

__global__ __launch_bounds__(256) void scatter_edges(
    const int* __restrict__ src, const int* __restrict__ dst,
    int* __restrict__ cursor, int* __restrict__ edst)
{
    int i = blockIdx.x * 256 + threadIdx.x;
    if (i < N_EDGES) {
        int pos = atomicAdd(&cursor[src[i]], 1);
        edst[pos] = dst[i];
    }
}

// ---------------------------------------------------------------------------
// Sliced gather-max. blockIdx & 7 = channel slice = XCD (round-robin dispatch
// heuristic): XCD s only touches u-slice s (3.2 MB, L2-resident) so the
// 16x row reuse is served by its own L2.
// ---------------------------------------------------------------------------
__device__ __forceinline__ float bflo(unsigned int w) {
    return __uint_as_float(w << 16);
}
__device__ __forceinline__ float bfhi(unsigned int w) {
    return __uint_as_float(w & 0xFFFF0000u);
}

__global__ __launch_bounds__(256) void gather_slice(
    const int* __restrict__ off, const int* __restrict__ edst,
    const unsigned short* __restrict__ u, const float* __restrict__ v,
    float* __restrict__ out, float* __restrict__ sums, float* __restrict__ sumsq)
{
    const int slice = blockIdx.x & 7;
    const int chunk = blockIdx.x >> 3;
    const int wave = threadIdx.x >> 6;
    const int lane = threadIdx.x & 63;
    const int g = lane >> 4;      // edge group 0..3
    const int l16 = lane & 15;    // channel-pair index within slice

    const unsigned short* ubase = u + (size_t)slice * N_NODES * SLC;
    const float* vbase = v + (size_t)slice * N_NODES * SLC;

    float s1_0 = 0.f, s1_1 = 0.f, s2_0 = 0.f, s2_1 = 0.f;

    for (int i = 0; i < NPB / 4; ++i) {
        const int n = chunk * NPB + wave * (NPB / 4) + i;
        if (n >= N_NODES) break;
        const int start = off[n];
        const int end = off[n + 1];
        float a0 = 0.f, a1 = 0.f;
        if (end > start) {
            float m0 = -INFINITY, m1 = -INFINITY;
            const int lim = end - 1;
            for (int e = start; e < end; e += 8) {
                int iA = min(e + g, lim);
                int iB = min(e + 4 + g, lim);
                int dA = edst[iA];                 // broadcast within group
                int dB = edst[iB];
                unsigned int wA = *(const unsigned int*)(ubase + (size_t)dA * SLC + l16 * 2);
                unsigned int wB = *(const unsigned int*)(ubase + (size_t)dB * SLC + l16 * 2);
                m0 = fmaxf(m0, fmaxf(bflo(wA), bflo(wB)));
                m1 = fmaxf(m1, fmaxf(bfhi(wA), bfhi(wB)));
            }
            m0 = fmaxf(m0, __shfl_xor(m0, 16));
            m0 = fmaxf(m0, __shfl_xor(m0, 32));
            m1 = fmaxf(m1, __shfl_xor(m1, 16));
            m1 = fmaxf(m1, __shfl_xor(m1, 32));
            float2 vv = *(const float2*)(vbase + (size_t)n * SLC + l16 * 2);
            a0 = fmaxf(vv.x + m0, 0.f);
            a1 = fmaxf(vv.y + m1, 0.f);
        }
        if (g == 0) {
            *(float2*)(out + (size_t)n * C_OUT + slice * SLC + l16 * 2) =
                make_float2(a0, a1);
            s1_0 += a0; s1_1 += a1;
            s2_0 += a0 * a0; s2_1 += a1 * a1;
        }
    }

    __shared__ float red[4][16][4];
    if (g == 0) {
        red[wave][l16][0] = s1_0; red[wave][l16][1] = s1_1;
        red[wave][l16][2] = s2_0; red[wave][l16][3] = s2_1;
    }
    __syncthreads();
    if (threadIdx.x < 16) {
        const int t = threadIdx.x;
        float r0 = 0.f, r1 = 0.f, r2 = 0.f, r3 = 0.f;
        #pragma unroll
        for (int w = 0; w < 4; ++w) {
            r0 += red[w][t][0]; r1 += red[w][t][1];
            r2 += red[w][t][2]; r3 += red[w][t][3];
        }
        const int c = slice * SLC + t * 2;
        atomicAdd(&sums[c + 0], r0);
        atomicAdd(&sums[c + 1], r1);
        atomicAdd(&sumsq[c + 0], r2);
        atomicAdd(&sumsq[c + 1], r3);
    }
}

// ---------------------------------------------------------------------------
// BatchNorm (batch stats, biased var) + ReLU, in place.
// ---------------------------------------------------------------------------
__global__ __launch_bounds__(256) void bn_apply(
    float* __restrict__ out, const float* __restrict__ sums,
    const float* __restrict__ sumsq, const float* __restrict__ gamma,
    const float* __restrict__ beta)
{
    const int idx = blockIdx.x * 256 + threadIdx.x;
    if (idx >= N_NODES * C_OUT) return;
    const int c = idx & (C_OUT - 1);
    const float inv_n = 1.f / (float)N_NODES;
    const float mean = sums[c] * inv_n;
    const float var = sumsq[c] * inv_n - mean * mean;
    const float scale = rsqrtf(var + BN_EPS) * gamma[c];
    float val = (out[idx] - mean) * scale + beta[c];
    out[idx] = fmaxf(val, 0.f);
}

extern "C" void kernel_launch(void* const* d_in, const int* in_sizes, int n_in,
                              void* d_out, int out_size, void* d_ws, size_t ws_size,
                              hipStream_t stream) {
    const float* x     = (const float*)d_in[0];
    const int*   src   = (const int*)d_in[1];
    const int*   dst   = (const int*)d_in[2];
    const float* theta = (const float*)d_in[3];
    const float* phi   = (const float*)d_in[4];
    const float* gamma = (const float*)d_in[5];
    const float* beta  = (const float*)d_in[6];
    float* out = (float*)d_out;

    // Workspace layout (16B-aligned chunks):
    char* ws = (char*)d_ws;
    const size_t uv_elems = (size_t)N_NODES * C_OUT;
    unsigned short* u = (unsigned short*)ws;                  // 25.6 MB bf16 slice-major
    float* v      = (float*)(ws + uv_elems * sizeof(unsigned short)); // 51.2 MB slice-major
    float* sums   = v + uv_elems;
    float* sumsq  = sums + C_OUT;
    int*   deg    = (int*)(sumsq + C_OUT);                    // contiguous w/ sums for one memset
    int*   off    = deg + N_NODES;                            // N_NODES+1 entries
    int*   cursor = off + N_NODES + 4;                        // pad keeps 16B align
    int*   edst   = cursor + N_NODES;                         // 3.2 MB
    int*   partials = edst + N_EDGES;                         // NBLK ints
    unsigned short* xb = (unsigned short*)(partials + NBLK + 8);   // 12.8 MB bf16
    unsigned short* wb = xb + (size_t)N_NODES * C_IN;              // 128 KB bf16

    // Zero sums, sumsq, deg in one shot (they are contiguous).
    hipMemsetAsync(sums, 0, (2 * C_OUT + N_NODES) * sizeof(int), stream);

    convert_x<<<(N_NODES * C_IN / 4 + 255) / 256, 256, 0, stream>>>(x, xb);
    convert_w<<<(512 * C_IN / 4 + 255) / 256, 256, 0, stream>>>(theta, phi, wb);

    dim3 gA((N_NODES + 127) / 128, 8);
    gemm_mfma<<<gA, 256, 0, stream>>>(xb, wb, u, v);

    const int EB = (N_EDGES + 255) / 256;
    hist_src<<<EB, 256, 0, stream>>>(src, deg);
    scan_part<<<NBLK, 256, 0, stream>>>(deg, partials);
    scan_mid<<<1, 256, 0, stream>>>(partials, off);
    scan_fin<<<NBLK, 256, 0, stream>>>(deg, partials, off, cursor);
    scatter_edges<<<EB, 256, 0, stream>>>(src, dst, cursor, edst);

    const int chunks = (N_NODES + NPB - 1) / NPB;
    gather_slice<<<chunks * SL, 256, 0, stream>>>(
        off, edst, u, v, out, sums, sumsq);

    bn_apply<<<(N_NODES * C_OUT + 255) / 256, 256, 0, stream>>>(
        out, sums, sumsq, gamma, beta);
}